// Round 2
// baseline (20609.306 us; speedup 1.0000x reference)
//
#include <hip/hip_runtime.h>
#include <hip/hip_bf16.h>

#define B_    32
#define T_    2048
#define F_    512
#define H_    512
#define G_    64          // workgroups (one per 8 h-columns)
#define NCOL  32          // z-columns per WG (4 gates x 8 h-cols)
#define WPITCH 520        // LDS pitch (shorts); 1040B row stride, 16B-aligned

typedef __attribute__((ext_vector_type(8))) short short8;   // 8 x bf16
typedef __attribute__((ext_vector_type(4))) float floatx4;  // MFMA acc / float4 loads

static __device__ __forceinline__ short bf16s(float f) {
    return __builtin_bit_cast(short, __float2bfloat16(f));
}

__device__ __forceinline__ float sigmoidf_(float x) {
    return 1.0f / (1.0f + __expf(-x));
}

// Device-wide barrier: every WG adds 1, tid0 spins until cnt reaches target.
// Agent-scope release/acquire handles cross-XCD L2 non-coherence (G16).
static __device__ __forceinline__ void gbar(unsigned int* cnt, unsigned target, int tid) {
    __syncthreads();                      // all WG stores drained (vmcnt(0) before s_barrier)
    if (tid == 0) {
        __hip_atomic_fetch_add(cnt, 1u, __ATOMIC_RELEASE, __HIP_MEMORY_SCOPE_AGENT);
        int spins = 0;
        while (__hip_atomic_load(cnt, __ATOMIC_ACQUIRE, __HIP_MEMORY_SCOPE_AGENT) < target) {
            __builtin_amdgcn_s_sleep(1);
            if (++spins > (1 << 27)) break;   // failsafe: fail fast, never hang
        }
    }
    __syncthreads();
}

__global__ __launch_bounds__(256, 1)
void lstm_persistent(const float* __restrict__ x,
                     const float* __restrict__ c0,
                     const float* __restrict__ h0,
                     const float* __restrict__ Wi,
                     const float* __restrict__ Wh,
                     const float* __restrict__ bias,
                     float* __restrict__ out,
                     __hip_bfloat16* __restrict__ hbuf,   // [2][B][H] bf16 ping-pong in ws
                     unsigned int* __restrict__ cnt)      // global barrier counter in ws
{
    // Transposed bf16 weight slices: wt[j][k] = bf16(W[k][gcol(j)]), j = gate*8 + hc
    __shared__ short wtI[NCOL][WPITCH];
    __shared__ short wtH[NCOL][WPITCH];
    __shared__ float zbuf[B_][NCOL + 1];

    const int tid = threadIdx.x;
    const int wg  = blockIdx.x;

    // ---- one-time: load + cvt Wi/Wh column slices (transposed) into LDS ----
    for (int idx = tid; idx < NCOL * F_; idx += 256) {
        const int j  = idx & (NCOL - 1);
        const int k  = idx >> 5;
        const int gi = j >> 3, hc = j & 7;
        const int gcol = gi * H_ + wg * 8 + hc;
        wtI[j][k] = bf16s(Wi[k * (4 * H_) + gcol]);
        wtH[j][k] = bf16s(Wh[k * (4 * H_) + gcol]);
    }

    // ---- one-time: cooperative h0 (fp32) -> hbuf slot 1 (bf16) ----
    {
        const int idx = wg * 256 + tid;            // 16384 threads == B*H elements
        hbuf[B_ * H_ + idx] = __float2bfloat16(h0[idx]);
    }

    // ---- gate-thread state: each thread owns one (batch, h) cell ----
    const int gb    = tid >> 3;          // 0..31
    const int ghc   = tid & 7;           // 0..7
    const int hglob = wg * 8 + ghc;
    float c_val  = c0[gb * H_ + hglob];
    float h_last = h0[gb * H_ + hglob];
    const float bi = bias[0 * H_ + hglob];
    const float bf = bias[1 * H_ + hglob];
    const float bg = bias[2 * H_ + hglob];
    const float bo = bias[3 * H_ + hglob];

    // ---- wave / MFMA tile ids ----
    const int wid  = tid >> 6;           // 0..3
    const int lane = tid & 63;
    const int mt   = wid >> 1;           // batch tile (rows 16*mt..+15)
    const int nt   = wid & 1;            // col tile  (cols 16*nt..+15)
    const int ln   = lane & 15;
    const int lq   = lane >> 4;

    const short* hbs = (const short*)hbuf;
    float* ys = out + 2 * B_ * H_;

    const int arow = mt * 16 + ln;       // A-operand batch row

    // h0 publish + LDS fill visible device-wide before step 0
    gbar(cnt, G_, tid);

    for (int t = 0; t < T_; ++t) {
        // ---- z-tile GEMM: bf16(x_t) @ WiSlice + h_{t-1} @ WhSlice ----
        const short* hrow = hbs + ((t - 1) & 1) * (B_ * H_) + arow * H_;
        const float* xrow = x + (arow * T_ + t) * F_;

        floatx4 accx = {0.f, 0.f, 0.f, 0.f};
        floatx4 acch = {0.f, 0.f, 0.f, 0.f};
        #pragma unroll
        for (int ks = 0; ks < 16; ++ks) {
            const int koff = ks * 32 + lq * 8;
            const floatx4 xa = *(const floatx4*)(xrow + koff);
            const floatx4 xb = *(const floatx4*)(xrow + koff + 4);
            short8 ax;
            ax[0] = bf16s(xa[0]); ax[1] = bf16s(xa[1]);
            ax[2] = bf16s(xa[2]); ax[3] = bf16s(xa[3]);
            ax[4] = bf16s(xb[0]); ax[5] = bf16s(xb[1]);
            ax[6] = bf16s(xb[2]); ax[7] = bf16s(xb[3]);
            const short8 ah = *(const short8*)(hrow + koff);
            const short8 bx = *(const short8*)&wtI[nt * 16 + ln][koff];
            const short8 bh = *(const short8*)&wtH[nt * 16 + ln][koff];
            accx = __builtin_amdgcn_mfma_f32_16x16x32_bf16(ax, bx, accx, 0, 0, 0);
            acch = __builtin_amdgcn_mfma_f32_16x16x32_bf16(ah, bh, acch, 0, 0, 0);
        }
        // C/D layout: col = lane&15, row = (lane>>4)*4 + reg  [m89-verified]
        {
            const int zrow = mt * 16 + lq * 4;
            const int zcol = nt * 16 + ln;
            #pragma unroll
            for (int r = 0; r < 4; ++r)
                zbuf[zrow + r][zcol] = accx[r] + acch[r];
        }
        __syncthreads();

        // ---- gates: one thread per (b, h) cell; c carried in fp32 register ----
        {
            const float zi = zbuf[gb][ghc]       + bi;
            const float zf = zbuf[gb][8  + ghc]  + bf;
            const float zg = zbuf[gb][16 + ghc]  + bg;
            const float zo = zbuf[gb][24 + ghc]  + bo;
            const float ig = sigmoidf_(zi);
            const float fg = sigmoidf_(zf);
            const float gg = tanhf(zg);
            const float og = sigmoidf_(zo);
            c_val  = fg * c_val + ig * gg;
            h_last = og * tanhf(c_val);
            hbuf[(t & 1) * (B_ * H_) + gb * H_ + hglob] = __float2bfloat16(h_last);
            ys[(gb * T_ + t) * H_ + hglob] = h_last;   // fp32 output
        }

        // ---- device-wide step barrier ----
        if (t + 1 < T_) {
            gbar(cnt, (unsigned)G_ * (unsigned)(t + 2), tid);
        }
    }

    // ---- finals: c_fin | h_fin (fp32) ----
    out[gb * H_ + hglob]            = c_val;
    out[B_ * H_ + gb * H_ + hglob] = h_last;
}

extern "C" void kernel_launch(void* const* d_in, const int* in_sizes, int n_in,
                              void* d_out, int out_size, void* d_ws, size_t ws_size,
                              hipStream_t stream) {
    const float* x  = (const float*)d_in[0];
    const float* c0 = (const float*)d_in[1];
    const float* h0 = (const float*)d_in[2];
    const float* Wi = (const float*)d_in[3];
    const float* Wh = (const float*)d_in[4];
    const float* b  = (const float*)d_in[5];
    float* out = (float*)d_out;

    unsigned char* ws = (unsigned char*)d_ws;
    unsigned int*   cnt  = (unsigned int*)ws;                 // [0,256): barrier counter
    __hip_bfloat16* hbuf = (__hip_bfloat16*)(ws + 256);       // [256, 256+64KiB): h ping-pong

    // ws is poisoned 0xAA before every timed launch: zero the barrier counter.
    hipMemsetAsync(d_ws, 0, 256, stream);

    void* args[] = { &x, &c0, &h0, &Wi, &Wh, &b, &out, &hbuf, &cnt };
    hipLaunchCooperativeKernel((void*)lstm_persistent, dim3(G_), dim3(256), args, 0, stream);
}

// Round 3
// 10278.245 us; speedup vs baseline: 2.0051x; 2.0051x over previous
//
#include <hip/hip_runtime.h>
#include <hip/hip_bf16.h>

#define B_    32
#define T_    2048
#define F_    512
#define H_    512
#define G_    64          // workgroups (one per 8 h-columns)
#define NCOL  32          // z-columns per WG (4 gates x 8 h-cols)
#define WPITCH 520        // LDS pitch (shorts) for transposed weight rows
#define SLOT  (B_ * H_)   // shorts per h slot (16384 = 32 KB)
#define DSL   64          // h-slot ring depth (4 MB); agent-acquire fence every DSL steps

typedef __attribute__((ext_vector_type(8))) short short8;   // 8 x bf16
typedef __attribute__((ext_vector_type(4))) float floatx4;

static __device__ __forceinline__ short bf16s(float f) {
    return __builtin_bit_cast(short, __float2bfloat16(f));
}
__device__ __forceinline__ float sigmoidf_(float x) {
    return 1.0f / (1.0f + __expf(-x));
}

// ---------------- prep: x fp32 -> bf16, h0 -> slot (DSL-1) ----------------
__global__ void prep_kernel(const float* __restrict__ x,
                            const float* __restrict__ h0,
                            unsigned short* __restrict__ xb,
                            unsigned short* __restrict__ h_slot_last,
                            int do_x)
{
    const int tid = threadIdx.x;
    if (blockIdx.x < 64) {
        const int idx = blockIdx.x * 256 + tid;          // 16384 == B*H
        h_slot_last[idx] = (unsigned short)bf16s(h0[idx]);
        return;
    }
    if (!do_x) return;
    const long long base = ((long long)(blockIdx.x - 64) * 256 + tid) * 8;
    const floatx4 a = *(const floatx4*)(x + base);
    const floatx4 b = *(const floatx4*)(x + base + 4);
    short8 s;
    s[0] = bf16s(a[0]); s[1] = bf16s(a[1]); s[2] = bf16s(a[2]); s[3] = bf16s(a[3]);
    s[4] = bf16s(b[0]); s[5] = bf16s(b[1]); s[6] = bf16s(b[2]); s[7] = bf16s(b[3]);
    *(short8*)(xb + base) = s;
}

// ---------------- persistent recurrent kernel ----------------
template<bool XB>
__global__ __launch_bounds__(256, 1)
void lstm_loop(const float* __restrict__ x,
               const unsigned short* __restrict__ xb,
               const float* __restrict__ c0,
               const float* __restrict__ Wi,
               const float* __restrict__ Wh,
               const float* __restrict__ bias,
               float* __restrict__ out,
               unsigned short* __restrict__ hbuf,   // [DSL][B][H] bf16 ring in ws
               unsigned int* __restrict__ flags)    // [G_] per-WG step counters
{
    __shared__ short wtI[NCOL][WPITCH];
    __shared__ short wtH[NCOL][WPITCH];
    __shared__ float zbuf[B_][NCOL + 1];
    __shared__ __align__(16) unsigned short h_lds[B_][8];

    const int tid = threadIdx.x;
    const int wg  = blockIdx.x;

    // one-time: transposed bf16 weight slices into LDS
    for (int idx = tid; idx < NCOL * F_; idx += 256) {
        const int j  = idx & (NCOL - 1);
        const int k  = idx >> 5;
        const int gi = j >> 3, hc = j & 7;
        const int gcol = gi * H_ + wg * 8 + hc;
        wtI[j][k] = bf16s(Wi[k * (4 * H_) + gcol]);
        wtH[j][k] = bf16s(Wh[k * (4 * H_) + gcol]);
    }

    // gate-thread state: one (batch, h) cell per thread
    const int gb    = tid >> 3;
    const int ghc   = tid & 7;
    const int hglob = wg * 8 + ghc;
    float c_val  = c0[gb * H_ + hglob];
    float h_last = 0.f;
    const float bi = bias[0 * H_ + hglob];
    const float bf = bias[1 * H_ + hglob];
    const float bg = bias[2 * H_ + hglob];
    const float bo = bias[3 * H_ + hglob];

    // wave / MFMA tile ids
    const int wid  = tid >> 6;
    const int lane = tid & 63;
    const int mt   = wid >> 1;           // batch tile
    const int nt   = wid & 1;            // col tile
    const int ln   = lane & 15;
    const int lq   = lane >> 4;
    const int arow = mt * 16 + ln;

    float* ys = out + 2 * B_ * H_;

    __syncthreads();   // LDS weights ready

    for (int t = 0; t < T_; ++t) {
        // ---- x-part GEMM first: independent of recurrence, overlaps others' tails ----
        floatx4 accx = {0.f, 0.f, 0.f, 0.f};
        if (XB) {
            const unsigned short* xrow = xb + (arow * T_ + t) * F_;
            #pragma unroll
            for (int ks = 0; ks < 16; ++ks) {
                const int koff = ks * 32 + lq * 8;
                const short8 ax = *(const short8*)(xrow + koff);
                const short8 bx = *(const short8*)&wtI[nt * 16 + ln][koff];
                accx = __builtin_amdgcn_mfma_f32_16x16x32_bf16(ax, bx, accx, 0, 0, 0);
            }
        } else {
            const float* xrow = x + (arow * T_ + t) * F_;
            #pragma unroll
            for (int ks = 0; ks < 16; ++ks) {
                const int koff = ks * 32 + lq * 8;
                const floatx4 xa = *(const floatx4*)(xrow + koff);
                const floatx4 xc = *(const floatx4*)(xrow + koff + 4);
                short8 ax;
                ax[0] = bf16s(xa[0]); ax[1] = bf16s(xa[1]);
                ax[2] = bf16s(xa[2]); ax[3] = bf16s(xa[3]);
                ax[4] = bf16s(xc[0]); ax[5] = bf16s(xc[1]);
                ax[6] = bf16s(xc[2]); ax[7] = bf16s(xc[3]);
                const short8 bx = *(const short8*)&wtI[nt * 16 + ln][koff];
                accx = __builtin_amdgcn_mfma_f32_16x16x32_bf16(ax, bx, accx, 0, 0, 0);
            }
        }

        // ---- wait for h_{t-1}: relaxed sc1 spin on per-WG flags (no invalidates) ----
        if (t > 0) {
            if (wid == 0) {
                int spins = 0;
                while (true) {
                    const unsigned f = __hip_atomic_load(&flags[lane], __ATOMIC_RELAXED,
                                                         __HIP_MEMORY_SCOPE_AGENT);
                    if (__all((int)(f >= (unsigned)t))) break;
                    if (++spins > (1 << 16)) break;   // deadlock failsafe: fail fast
                }
            }
            __syncthreads();
            // slot-reuse safety: one L1/L2 invalidate per DSL steps (covers ring wrap)
            if ((t & (DSL - 1)) == 0)
                __builtin_amdgcn_fence(__ATOMIC_ACQUIRE, "agent");
        }

        // ---- h-part GEMM: plain 16B loads (lines never stale: ring + periodic fence) ----
        const unsigned short* hrow = hbuf + ((t - 1) & (DSL - 1)) * SLOT + arow * H_;
        floatx4 acch = {0.f, 0.f, 0.f, 0.f};
        #pragma unroll
        for (int ks = 0; ks < 16; ++ks) {
            const int koff = ks * 32 + lq * 8;
            const short8 ah = *(const short8*)(hrow + koff);
            const short8 bh = *(const short8*)&wtH[nt * 16 + ln][koff];
            acch = __builtin_amdgcn_mfma_f32_16x16x32_bf16(ah, bh, acch, 0, 0, 0);
        }
        // C/D layout: col = lane&15, row = (lane>>4)*4 + reg  [m89-verified]
        {
            const int zrow = mt * 16 + lq * 4;
            const int zcol = nt * 16 + ln;
            #pragma unroll
            for (int r = 0; r < 4; ++r)
                zbuf[zrow + r][zcol] = accx[r] + acch[r];
        }
        __syncthreads();

        // ---- gates ----
        {
            const float zi = zbuf[gb][ghc]       + bi;
            const float zf = zbuf[gb][8  + ghc]  + bf;
            const float zg = zbuf[gb][16 + ghc]  + bg;
            const float zo = zbuf[gb][24 + ghc]  + bo;
            const float ig = sigmoidf_(zi);
            const float fg = sigmoidf_(zf);
            const float gg = tanhf(zg);
            const float og = sigmoidf_(zo);
            c_val  = fg * c_val + ig * gg;
            h_last = og * tanhf(c_val);
            h_lds[gb][ghc] = (unsigned short)bf16s(h_last);
            ys[(gb * T_ + t) * H_ + hglob] = h_last;   // fp32 output, plain store
        }
        __syncthreads();

        // ---- publish h_t: write-through agent stores (8B packed), then flag ----
        if (tid < 64) {
            const int row = tid >> 1, c4 = (tid & 1) * 4;
            const unsigned long long v = *(const unsigned long long*)&h_lds[row][c4];
            __hip_atomic_store((unsigned long long*)(hbuf + (t & (DSL - 1)) * SLOT
                                                     + row * H_ + wg * 8 + c4),
                               v, __ATOMIC_RELAXED, __HIP_MEMORY_SCOPE_AGENT);
        }
        __syncthreads();   // wave0's publish stores drained (vmcnt0) before flag
        if (tid == 0)
            __hip_atomic_store(&flags[wg], (unsigned)(t + 1), __ATOMIC_RELAXED,
                               __HIP_MEMORY_SCOPE_AGENT);
    }

    // finals: c_fin | h_fin (fp32)
    out[gb * H_ + hglob]           = c_val;
    out[B_ * H_ + gb * H_ + hglob] = h_last;
}

extern "C" void kernel_launch(void* const* d_in, const int* in_sizes, int n_in,
                              void* d_out, int out_size, void* d_ws, size_t ws_size,
                              hipStream_t stream) {
    const float* x  = (const float*)d_in[0];
    const float* c0 = (const float*)d_in[1];
    const float* h0 = (const float*)d_in[2];
    const float* Wi = (const float*)d_in[3];
    const float* Wh = (const float*)d_in[4];
    const float* b  = (const float*)d_in[5];
    float* out = (float*)d_out;

    unsigned char* ws = (unsigned char*)d_ws;
    unsigned int*   flags = (unsigned int*)ws;                       // [0, 4KB)
    unsigned short* hbuf  = (unsigned short*)(ws + 65536);           // DSL slots * 32 KB = 4 MB
    unsigned short* xb    = (unsigned short*)(ws + 65536 + (size_t)DSL * SLOT * 2);

    const size_t need_xb = 65536 + (size_t)DSL * SLOT * 2 + (size_t)B_ * T_ * F_ * 2;
    const int use_xb = (ws_size >= need_xb) ? 1 : 0;

    // flags poisoned 0xAA before every timed launch: zero them
    hipMemsetAsync(ws, 0, 4096, stream);

    const int prep_blocks = 64 + (use_xb ? (B_ * T_ * F_ / 8 / 256) : 0);
    prep_kernel<<<prep_blocks, 256, 0, stream>>>(x, h0, xb, hbuf + (DSL - 1) * SLOT, use_xb);

    void* args[] = { &x, &xb, &c0, &Wi, &Wh, &b, &out, &hbuf, &flags };
    hipLaunchCooperativeKernel(use_xb ? (void*)lstm_loop<true> : (void*)lstm_loop<false>,
                               dim3(G_), dim3(256), args, 0, stream);
}